// Round 2
// 1933.176 us; speedup vs baseline: 1.0766x; 1.0766x over previous
//
#include <hip/hip_runtime.h>
#include <stdint.h>

typedef unsigned int u32;
typedef unsigned long long u64;

#define Bb 4
#define Nn 8192
#define Dd 64
#define Kk 32
#define MAXIT 30
#define NBLK 128   // 4 batches x 32 blocks, 256 threads = 1 point/thread

// ---- workspace layout (bytes); total ~6.35 MB ----
enum : u32 {
  WS_BAR   = 0u,        // 2 u32 barrier state (zeroed by kinit)
  WS_SEL   = 64u,       // 32 u32
  WS_MASKH = 192u,      // [par][4*32] u32 masks of head points
  WS_C0    = 1280u,     // 4*32*64 f
  WS_XHEAD = 34048u,    // 4*32*64 f  (mutable first-32 rows of X)
  WS_KEYS1 = 66816u,    // 8192 u32
  WS_KEYS2 = 99584u,
  WS_A1K   = 132352u,   // sorted (key,idx) round 1
  WS_A1V   = 165120u,
  WS_A2K   = 197888u,
  WS_A2V   = 230656u,
  WS_PCHG  = 263424u,   // [par][128] u32
  WS_PCNT  = 264448u,   // [par][4][32][32] u32
  WS_POBJ  = 297216u,   // [4][32] f
  WS_PMIN  = 297728u,   // [4][32 k][32 blk] u64 packed (dist,idx)
  WS_PSUM  = 330496u,   // [par][4][32][2080] f  (2048 sums d-major + 32 W)
  WS_DM    = 2460416u   // [4][32][8192] f final distances
};

// Threefry-2x32, 20 rounds — matches jax._src.prng
__device__ __forceinline__ void tf2x32(u32 k0, u32 k1, u32 x0, u32 x1, u32& o0, u32& o1){
  u32 ks2 = k0 ^ k1 ^ 0x1BD11BDAu;
  x0 += k0; x1 += k1;
#define TFR(r) { x0 += x1; x1 = (x1<<(r))|(x1>>(32-(r))); x1 ^= x0; }
  TFR(13) TFR(15) TFR(26) TFR(6)
  x0 += k1;  x1 += ks2 + 1u;
  TFR(17) TFR(29) TFR(16) TFR(24)
  x0 += ks2; x1 += k0 + 2u;
  TFR(13) TFR(15) TFR(26) TFR(6)
  x0 += k0;  x1 += k1 + 3u;
  TFR(17) TFR(29) TFR(16) TFR(24)
  x0 += k1;  x1 += ks2 + 4u;
  TFR(13) TFR(15) TFR(26) TFR(6)
  x0 += ks2; x1 += k0 + 5u;
#undef TFR
  o0 = x0; o1 = x1;
}

// ---------------- init kernel: PRNG + 2 stable sorts + C0/Xhead/barrier init ----
__global__ __launch_bounds__(1024, 1) void kinit(const float* __restrict__ E, char* __restrict__ ws){
  const int tid = threadIdx.x;
  u32* bar   = (u32*)(ws + WS_BAR);
  u32* sel   = (u32*)(ws + WS_SEL);
  u32* keys1 = (u32*)(ws + WS_KEYS1);
  u32* keys2 = (u32*)(ws + WS_KEYS2);
  u32* a1k = (u32*)(ws + WS_A1K); u32* a1v = (u32*)(ws + WS_A1V);
  u32* a2k = (u32*)(ws + WS_A2K); u32* a2v = (u32*)(ws + WS_A2V);
  float* C0 = (float*)(ws + WS_C0);
  float* XH = (float*)(ws + WS_XHEAD);

  __shared__ u32 hist[8192];
  __shared__ u32 lsum[1024];
  __shared__ u32 sel_s[32];

  if (tid < 4) bar[tid] = 0u;

  // key chain (threefry_partitionable=True semantics):
  // root=(0,42); k_init = enc_root(0,0)
  u32 i0,i1; tf2x32(0u,42u, 0u,0u, i0,i1);
  // round1: key1 = enc_kinit(0,0); sub1 = enc_kinit(0,1)
  u32 key10,key11, s10,s11;
  tf2x32(i0,i1, 0u,0u, key10,key11);
  tf2x32(i0,i1, 0u,1u, s10,s11);
  // round2: sub2 = enc_key1(0,1)
  u32 s20,s21; tf2x32(key10,key11, 0u,1u, s20,s21);

  // sort keys: bits32 = y0 ^ y1 of enc_sub(0, i)   (partitionable random_bits)
  for (int i = tid; i < 8192; i += 1024){
    u32 y0,y1;
    tf2x32(s10,s11, 0u,(u32)i, y0,y1); keys1[i] = y0 ^ y1;
    tf2x32(s20,s21, 0u,(u32)i, y0,y1); keys2[i] = y0 ^ y1;
  }
  // Xhead = first 32 rows of each batch
  for (int i = tid; i < 8192; i += 1024){
    int b = i >> 11; int rem = i & 2047;
    XH[i] = E[(size_t)b*Nn*Dd + rem];
  }
  __syncthreads();

  // two stable sorts: bucket by top 13 bits, insertion-sort buckets by (key, idx)
  for (int rnd = 0; rnd < 2; rnd++){
    u32* keys = rnd ? keys2 : keys1;
    u32* ak   = rnd ? a2k   : a1k;
    u32* av   = rnd ? a2v   : a1v;
    for (int i = tid; i < 8192; i += 1024) hist[i] = 0u;
    __syncthreads();
    for (int i = tid; i < 8192; i += 1024) atomicAdd(&hist[keys[i]>>19], 1u);
    __syncthreads();
    // exclusive scan of 8192 buckets
    { u32 s = 0;
      for (int j = 0; j < 8; j++) s += hist[tid*8+j];
      lsum[tid] = s; }
    __syncthreads();
    for (int st = 1; st < 1024; st <<= 1){
      u32 v = (tid >= st) ? lsum[tid-st] : 0u;
      __syncthreads();
      lsum[tid] += v;
      __syncthreads();
    }
    { u32 run = tid ? lsum[tid-1] : 0u;
      for (int j = 0; j < 8; j++){ u32 c = hist[tid*8+j]; hist[tid*8+j] = run; run += c; } }
    __syncthreads();
    // scatter (hist becomes end-offsets)
    for (int i = tid; i < 8192; i += 1024){
      u32 kx = keys[i];
      u32 pos = atomicAdd(&hist[kx>>19], 1u);
      ak[pos] = kx; av[pos] = (u32)i;
    }
    __syncthreads();
    // per-bucket insertion sort -> total order == stable sort by key
    for (int bkt = tid; bkt < 8192; bkt += 1024){
      int s0 = bkt ? (int)hist[bkt-1] : 0;
      int e0 = (int)hist[bkt];
      for (int i = s0+1; i < e0; i++){
        u32 kx = ak[i], vx = av[i];
        int j = i-1;
        while (j >= s0 && (ak[j] > kx || (ak[j] == kx && av[j] > vx))){
          ak[j+1] = ak[j]; av[j+1] = av[j]; j--;
        }
        ak[j+1] = kx; av[j+1] = vx;
      }
    }
    __syncthreads();
  }
  // sel[j] = perm2[j] = perm1[pos of j-th smallest keys2]
  if (tid < 32){ u32 p = a2v[tid]; u32 sj = a1v[p]; sel[tid] = sj; sel_s[tid] = sj; }
  __syncthreads();
  // C0[b][k][d] = E[b][sel[k]][d]
  for (int i = tid; i < 8192; i += 1024){
    int b = i >> 11; int k = (i >> 6) & 31; int d = i & 63;
    C0[i] = E[(size_t)b*Nn*Dd + (size_t)sel_s[k]*Dd + d];
  }
}

// device-scope sense-reversing grid barrier (128 co-resident blocks)
// Fence-minimal protocol:
//  - arrival: RELEASE fetch_add  -> publishes this block's stores (one wbl2)
//  - spin:    RELAXED agent load (sc1, reads coherence point; no per-poll inv)
//             + forward-progress hedge: one ACQUIRE load every 64 polls, in case
//             relaxed agent loads don't bypass stale cache levels on gfx950
//  - wake:    single ACQUIRE agent fence (one buffer_inv) before reading remote data
// The flag read observing the RELEASE store + the acquire fence forms the
// synchronizes-with edge, so all pre-barrier stores of all blocks are visible.
__device__ __forceinline__ void grid_barrier(u32* bar){
  __syncthreads();
  if (threadIdx.x == 0){
    u32 g = __hip_atomic_load(&bar[1], __ATOMIC_RELAXED, __HIP_MEMORY_SCOPE_AGENT);
    u32 a = __hip_atomic_fetch_add(&bar[0], 1u, __ATOMIC_RELEASE, __HIP_MEMORY_SCOPE_AGENT);
    if (a == (u32)(NBLK-1)){
      __hip_atomic_store(&bar[0], 0u, __ATOMIC_RELAXED, __HIP_MEMORY_SCOPE_AGENT);
      __hip_atomic_store(&bar[1], g + 1u, __ATOMIC_RELEASE, __HIP_MEMORY_SCOPE_AGENT);
    } else {
      int polls = 0;
      for (;;){
        u32 v = __hip_atomic_load(&bar[1], __ATOMIC_RELAXED, __HIP_MEMORY_SCOPE_AGENT);
        if (v != g) break;
        if ((++polls & 63) == 0){
          // hedge: guarantees visibility even if relaxed polls could go stale
          v = __hip_atomic_load(&bar[1], __ATOMIC_ACQUIRE, __HIP_MEMORY_SCOPE_AGENT);
          if (v != g) break;
        }
        __builtin_amdgcn_s_sleep(2);
      }
    }
    __builtin_amdgcn_fence(__ATOMIC_ACQUIRE, "agent");
  }
  __syncthreads();
}

#define CALC_XX() do { float s0=0.f,s1=0.f,s2=0.f,s3=0.f; \
  _Pragma("unroll") \
  for (int j=0;j<16;j++){ s0+=x[4*j]*x[4*j]; s1+=x[4*j+1]*x[4*j+1]; s2+=x[4*j+2]*x[4*j+2]; s3+=x[4*j+3]*x[4*j+3]; } \
  xx=(s0+s1)+(s2+s3); } while(0)

#define CALC_DIST() do { \
  _Pragma("unroll") \
  for (int k=0;k<32;k++){ \
    const float4* cp = (const float4*)&Cl[k*64]; \
    float s0=0.f,s1=0.f,s2=0.f,s3=0.f; \
    _Pragma("unroll") \
    for (int j=0;j<16;j++){ float4 c = cp[j]; s0+=x[4*j]*c.x; s1+=x[4*j+1]*c.y; s2+=x[4*j+2]*c.z; s3+=x[4*j+3]*c.w; } \
    float dot=(s0+s1)+(s2+s3); \
    dloc[k]=(ccl[k]+xx)-2.f*dot; \
  } } while(0)

__global__ __launch_bounds__(256, 1) void kmain(const float* __restrict__ E, const float* __restrict__ LW,
                                                float* __restrict__ out, char* __restrict__ ws){
  const int tid = threadIdx.x;
  const int bid = blockIdx.x;
  const int b   = bid >> 5;
  const int blk = bid & 31;
  const int n   = (blk << 8) + tid;

  u32*   bar   = (u32*)(ws + WS_BAR);
  u32*   maskh = (u32*)(ws + WS_MASKH);
  float* C0    = (float*)(ws + WS_C0);
  float* XH    = (float*)(ws + WS_XHEAD);
  u32*   Pchg  = (u32*)(ws + WS_PCHG);
  u32*   Pcnt  = (u32*)(ws + WS_PCNT);
  float* Pobj  = (float*)(ws + WS_POBJ);
  u64*   Pmin  = (u64*)(ws + WS_PMIN);
  float* Psum  = (float*)(ws + WS_PSUM);
  float* Dm    = (float*)(ws + WS_DM);

  __shared__ float Cl[2048];      // C[k][d] (k-major, float4 broadcast reads)
  __shared__ float ccl[32];
  __shared__ float part[2080];    // sums d-major: part[d*32+k]; W at part[2048+k]
  __shared__ u32   cntl[32];
  __shared__ u32   cntall[128];   // reduced counts, all batches
  __shared__ u32   chg_s[128];
  __shared__ float newX[2048];    // replacement rows staging / rep accumulator
  __shared__ u64   kminl[32];
  __shared__ float red[256];
  __shared__ u32   sh_chg, sh_empty, sh_idx, sh_tcnt;
  __shared__ float sh_mind;

  // load this thread's point into registers
  float x[64]; float xx;
  { const float4* xr = (const float4*)(E + (size_t)(b*Nn + n)*Dd);
    #pragma unroll
    for (int j=0;j<16;j++){ float4 v = xr[j]; x[4*j]=v.x; x[4*j+1]=v.y; x[4*j+2]=v.z; x[4*j+3]=v.w; } }
  CALC_XX();
  const float w = expf(LW[b*Nn + n]);  // weight is positional, constant

  // k_loop = enc_(0,42)(0,1)  (for empty-cluster randint path)
  u32 kl0, kl1; tf2x32(0u,42u, 0u,1u, kl0, kl1);

  for (int i = tid; i < 2048; i += 256) Cl[i] = C0[b*2048 + i];
  __syncthreads();
  if (tid < 32){ float s=0.f; const float* cr=&Cl[tid*64];
    #pragma unroll
    for (int d2=0; d2<64; d2++) s += cr[d2]*cr[d2];
    ccl[tid]=s; }
  __syncthreads();

  u32 prevmask = 0u;
  float dloc[32];

  for (int t = 0; t < MAXIT; t++){
    const int par = t & 1;
    // ---------- phase 1: assignment + per-block partial sums ----------
    CALC_DIST();
    float mind = dloc[0];
    #pragma unroll
    for (int k=1;k<32;k++) mind = fminf(mind, dloc[k]);
    u32 mask = 0u;
    #pragma unroll
    for (int k=0;k<32;k++) if (fabsf(dloc[k]-mind) < 1e-8f) mask |= (1u<<k);
    int changed = (t==0) ? 1 : (mask != prevmask);
    prevmask = mask;
    if (blk == 0 && tid < 32) maskh[par*128 + b*32 + tid] = mask;

    __syncthreads();
    for (int i = tid; i < 2080; i += 256) part[i] = 0.f;
    if (tid < 32) cntl[tid] = 0u;
    __syncthreads();
    { u32 mm = mask;
      while (mm){
        int k = __ffs(mm) - 1; mm &= mm - 1;
        #pragma unroll
        for (int d2=0; d2<64; d2++) atomicAdd(&part[d2*32 + k], w*x[d2]);
        atomicAdd(&part[2048 + k], w);
        atomicAdd(&cntl[k], 1u);
      } }
    int nchg = __syncthreads_count(changed);
    { float* dst = Psum + (size_t)(((par*4)+b)*32 + blk) * 2080;
      for (int i = tid; i < 2080; i += 256) dst[i] = part[i];
      if (tid < 32) Pcnt[(((par*4)+b)*32 + blk)*32 + tid] = cntl[tid];
      if (tid == 0) Pchg[par*128 + bid] = (u32)nchg; }
    grid_barrier(bar);

    // ---------- phase 2: every block reduces -> its own C in LDS ----------
    if (tid < 128){
      u32 s = 0; int bb = tid >> 5, kq = tid & 31;
      for (int bl = 0; bl < 32; bl++) s += Pcnt[(((par*4)+bb)*32 + bl)*32 + kq];
      cntall[tid] = s;
      chg_s[tid] = Pchg[par*128 + tid];
    }
    __syncthreads();
    if (tid == 0){
      u32 c = 0, ae = 0;
      for (int i2 = 0; i2 < 128; i2++){ c += chg_s[i2]; ae |= (cntall[i2] == 0u) ? 1u : 0u; }
      sh_chg = c; sh_empty = ae;
    }
    __syncthreads();
    if (sh_chg == 0u) break;   // global convergence: state frozen (matches reference)

    { const float* src = Psum + (size_t)(((par*4)+b)*32) * 2080;
      for (int i = tid; i < 2080; i += 256){
        float s = 0.f;
        for (int bl = 0; bl < 32; bl++) s += src[bl*2080 + i];
        part[i] = s;
      } }
    __syncthreads();

    if (sh_empty){
      // empty-cluster replacement: X rows j (=cluster idx) replaced BEFORE C update,
      // weights/assignments from pre-replacement X. All blocks apply identical fixup.
      u32 g0, g1; tf2x32(kl0, kl1, 0u, (u32)t, g0, g1);   // fold_in(k_loop, t)
      for (int k = 0; k < 32; k++){
        if (cntall[b*32 + k] != 0u) continue;
        int j = b*32 + k;
        u32 y0, y1; tf2x32(g0, g1, 0u, (u32)j, y0, y1);   // partitionable bits: y0^y1
        u32 ridx = (y0 ^ y1) & 8191u;
        u32 mj = maskh[par*128 + b*32 + k];
        float wj = expf(LW[b*Nn + k]);
        if (tid < 64){
          float xo = XH[(b*32 + k)*64 + tid];
          float xn = (ridx < 32u) ? XH[(b*32 + (int)ridx)*64 + tid]
                                  : E[(size_t)(b*Nn + (int)ridx)*Dd + tid];
          newX[k*64 + tid] = xn;
          float dxw = wj * (xn - xo);
          u32 m2 = mj;
          while (m2){ int kq = __ffs(m2) - 1; m2 &= m2 - 1; part[tid*32 + kq] += dxw; }
        }
      }
      __syncthreads();
      grid_barrier(bar);      // all fixup reads of old Xhead complete before writes
      if (blk == 0){
        for (int k = 0; k < 32; k++){
          if (cntall[b*32 + k] != 0u) continue;
          if (tid < 64) XH[(b*32 + k)*64 + tid] = newX[k*64 + tid];
        }
        __syncthreads();
        if (tid < 32 && cntall[b*32 + tid] == 0u){
          #pragma unroll
          for (int d2 = 0; d2 < 64; d2++) x[d2] = newX[tid*64 + d2];
          CALC_XX();
        }
      }
    }
    __syncthreads();
    // C_new = sums / clip(W, 1e-12)  (empty -> 0, matching reference)
    for (int i = tid; i < 2048; i += 256){
      int k = i >> 6, d = i & 63;
      Cl[i] = part[d*32 + k] / fmaxf(part[2048 + k], 1e-12f);
    }
    __syncthreads();
    if (tid < 32){ float s=0.f; const float* cr=&Cl[tid*64];
      #pragma unroll
      for (int d2=0; d2<64; d2++) s += cr[d2]*cr[d2];
      ccl[tid]=s; }
    __syncthreads();
  }

  // ---------- finalize 1: Dm with final C; ass from LAST assignment; partial mins/obj ----------
  CALC_DIST();
  float mind = dloc[0];
  #pragma unroll
  for (int k=1;k<32;k++) mind = fminf(mind, dloc[k]);
  #pragma unroll
  for (int k=0;k<32;k++) Dm[(size_t)(b*32 + k)*Nn + n] = dloc[k];
  { float4* dst = (float4*)(out + (size_t)(b*Nn + n)*32);
    #pragma unroll
    for (int q=0;q<8;q++){
      float4 v;
      v.x = ((prevmask>>(4*q  ))&1u) ? 1.f : 0.f;
      v.y = ((prevmask>>(4*q+1))&1u) ? 1.f : 0.f;
      v.z = ((prevmask>>(4*q+2))&1u) ? 1.f : 0.f;
      v.w = ((prevmask>>(4*q+3))&1u) ? 1.f : 0.f;
      dst[q] = v;
    } }
  if (tid < 32) kminl[tid] = ~0ull;
  red[tid] = mind;
  __syncthreads();
  #pragma unroll
  for (int k=0;k<32;k++){
    u32 u = __float_as_uint(dloc[k]);
    u = (u & 0x80000000u) ? ~u : (u | 0x80000000u);  // monotone encode (handles negatives)
    u64 pk = ((u64)u << 32) | (u32)n;                // tie -> smaller n (first argmin)
    atomicMin(&kminl[k], pk);
  }
  for (int s2 = 128; s2 > 0; s2 >>= 1){
    if (tid < s2) red[tid] += red[tid + s2];
    __syncthreads();
  }
  if (tid < 32) Pmin[(size_t)(b*32 + tid)*32 + blk] = kminl[tid];
  if (tid == 0) Pobj[b*32 + blk] = red[0];
  grid_barrier(bar);

  // ---------- finalize 2: block -> (b2,k2): rep_idx, rep, C, obj ----------
  {
    const int b2 = bid >> 5, k2 = bid & 31;
    const size_t OFF_C    = (size_t)Bb*Nn*Kk;        // 1048576
    const size_t OFF_REP  = OFF_C + (size_t)Bb*Kk*Dd;
    const size_t OFF_RIDX = OFF_REP + (size_t)Bb*Kk*Dd;
    const size_t OFF_OBJ  = OFF_RIDX + (size_t)Bb*Kk;
    if (tid == 0){
      u64 m = ~0ull;
      for (int bl = 0; bl < 32; bl++){ u64 v = Pmin[(size_t)(b2*32 + k2)*32 + bl]; if (v < m) m = v; }
      u32 enc = (u32)(m >> 32);
      u32 ub  = (enc & 0x80000000u) ? (enc & 0x7fffffffu) : ~enc;
      sh_mind = __uint_as_float(ub);
      sh_idx  = (u32)(m & 0xffffffffu);
      sh_tcnt = 0u;
    }
    if (tid < 64) newX[tid] = 0.f;   // rep accumulator
    __syncthreads();
    float mr = sh_mind;
    for (int nn = tid; nn < Nn; nn += 256){
      float dv = Dm[(size_t)(b2*32 + k2)*Nn + nn];
      if (fabsf(dv - mr) < 1e-8f){
        atomicAdd(&sh_tcnt, 1u);
        const float* xr = (nn < 32) ? &XH[(b2*32 + nn)*64] : &E[(size_t)(b2*Nn + nn)*Dd];
        for (int d2 = 0; d2 < 64; d2++) atomicAdd(&newX[d2], xr[d2]);
      }
    }
    __syncthreads();
    if (tid < 64){
      out[OFF_C   + (size_t)(b2*32 + k2)*64 + tid] = Cl[k2*64 + tid];
      out[OFF_REP + (size_t)(b2*32 + k2)*64 + tid] = newX[tid] / (float)sh_tcnt;
    }
    if (tid == 0) out[OFF_RIDX + b2*32 + k2] = (float)sh_idx;
    if (k2 == 0){
      if (tid < 32) red[tid] = Pobj[b2*32 + tid];
      __syncthreads();
      if (tid == 0){ float s = 0.f; for (int i2 = 0; i2 < 32; i2++) s += red[i2];
        out[OFF_OBJ + b2] = s / (float)Nn; }
    }
  }
}

extern "C" void kernel_launch(void* const* d_in, const int* in_sizes, int n_in,
                              void* d_out, int out_size, void* d_ws, size_t ws_size,
                              hipStream_t stream) {
  const float* E  = (const float*)d_in[0];
  const float* LW = (const float*)d_in[1];
  float* out = (float*)d_out;
  char*  ws  = (char*)d_ws;
  (void)in_sizes; (void)n_in; (void)out_size; (void)ws_size;
  kinit<<<dim3(1),    dim3(1024), 0, stream>>>(E, ws);
  kmain<<<dim3(NBLK), dim3(256),  0, stream>>>(E, LW, out, ws);
}